// Round 1
// baseline (167.351 us; speedup 1.0000x reference)
//
#include <hip/hip_runtime.h>
#include <stdint.h>

// Problem constants
#define D_DIM 512
#define B_ROWS 4096
#define N_ROWS 8192
// (1/TEMPERATURE) * log2(e) : exp(x/T) == exp2(x * SCALE_L2E)
#define SCALE_L2E 14.426950408889634f

typedef __attribute__((ext_vector_type(8))) __bf16 bf16x8;
typedef __attribute__((ext_vector_type(4))) float f32x4;

using gas1_t = const __attribute__((address_space(1))) void;
using las3_t = __attribute__((address_space(3))) void;
#define GLOAD16(g, l) __builtin_amdgcn_global_load_lds((gas1_t*)(g), (las3_t*)(l), 16, 0, 0)

// round-to-nearest-even float -> bf16 bits (inputs are sane randn-derived, no NaN path)
__device__ __forceinline__ unsigned short f2bf(float f) {
    union { float f; unsigned int u; } v; v.f = f;
    unsigned int u = v.u;
    unsigned int r = (u + 0x7FFFu + ((u >> 16) & 1u)) >> 16;
    return (unsigned short)r;
}

// ---------------- K1: normalize rows, write bf16 Zn, accumulate sum of positive logits ----
// block = 256 threads handles one index i: rows zi[i] -> Zn[i], zj[i] -> Zn[B+i]
__global__ __launch_bounds__(256) void k_normalize(const float* __restrict__ zi,
                                                   const float* __restrict__ zj,
                                                   unsigned short* __restrict__ Zn,
                                                   float* __restrict__ sums) {
    const int i = blockIdx.x;
    const int t = threadIdx.x;
    const float2 vi = *(const float2*)(zi + (size_t)i * D_DIM + t * 2);
    const float2 vj = *(const float2*)(zj + (size_t)i * D_DIM + t * 2);
    float ssi = vi.x * vi.x + vi.y * vi.y;
    float ssj = vj.x * vj.x + vj.y * vj.y;
    float dt  = vi.x * vj.x + vi.y * vj.y;
    #pragma unroll
    for (int off = 1; off < 64; off <<= 1) {
        ssi += __shfl_xor(ssi, off);
        ssj += __shfl_xor(ssj, off);
        dt  += __shfl_xor(dt,  off);
    }
    __shared__ float red[3][4];
    const int wid = t >> 6;
    if ((t & 63) == 0) { red[0][wid] = ssi; red[1][wid] = ssj; red[2][wid] = dt; }
    __syncthreads();
    ssi = red[0][0] + red[0][1] + red[0][2] + red[0][3];
    ssj = red[1][0] + red[1][1] + red[1][2] + red[1][3];
    dt  = red[2][0] + red[2][1] + red[2][2] + red[2][3];
    const float si = 1.0f / fmaxf(sqrtf(ssi), 1e-12f);
    const float sj = 1.0f / fmaxf(sqrtf(ssj), 1e-12f);
    unsigned int pi = (unsigned int)f2bf(vi.x * si) | ((unsigned int)f2bf(vi.y * si) << 16);
    unsigned int pj = (unsigned int)f2bf(vj.x * sj) | ((unsigned int)f2bf(vj.y * sj) << 16);
    *(unsigned int*)(Zn + (size_t)i * D_DIM + t * 2) = pi;
    *(unsigned int*)(Zn + (size_t)(B_ROWS + i) * D_DIM + t * 2) = pj;
    // positive logit appears twice in the loss (row i and row i+B): 2 * dot / T
    if (t == 0) atomicAdd(&sums[0], 20.0f * dt * si * sj);
}

// ---------------- K2: fused S = Zn·Zn^T (bf16 MFMA) + per-row sum(exp(S/T)), diag masked ---
// grid: (8 col-splits, 64 row-blocks); block = 256 threads = 4 waves (2x2), wave tile 64x64
// BK=64, single LDS buffer, 2 barriers per K-chunk. XOR-swizzled LDS (slot ^= row&7) with
// linear global_load_lds dest + pre-swizzled global source; ds_read applies same XOR.
#define BM 128
#define BK 64
#define COLS_PER_BLK 1024

__global__ __launch_bounds__(256) void k_gemm_lse(const unsigned short* __restrict__ Zn,
                                                  float* __restrict__ rowsum_g) {
    __shared__ __align__(16) unsigned short Als[BM * BK];  // 16 KiB
    __shared__ __align__(16) unsigned short Bls[BM * BK];  // 16 KiB
    const int t    = threadIdx.x;
    const int lane = t & 63;
    const int w    = t >> 6;
    const int wm   = w >> 1, wn = w & 1;
    const int l15  = lane & 15, lhi = lane >> 4;
    const int rowBase  = blockIdx.y * BM;
    const int colBase0 = blockIdx.x * COLS_PER_BLK;

    // staging geometry: thread t owns LDS bytes [h*4096 + t*16, +16) per h; row-of-128B layout
    const int srow = t >> 3;   // row within 32-row group
    const int slot = t & 7;    // 16B slot within 128B row

    f32x4 acc[4][4];
    float rowsum[4][4];
    #pragma unroll
    for (int a = 0; a < 4; ++a)
        #pragma unroll
        for (int b = 0; b < 4; ++b) rowsum[a][b] = 0.0f;

    for (int ct = 0; ct < COLS_PER_BLK / BM; ++ct) {
        const int colBase = colBase0 + ct * BM;
        #pragma unroll
        for (int a = 0; a < 4; ++a)
            #pragma unroll
            for (int b = 0; b < 4; ++b)
                #pragma unroll
                for (int q = 0; q < 4; ++q) acc[a][b][q] = 0.0f;

        for (int kc = 0; kc < D_DIM / BK; ++kc) {
            const int kbase = kc * BK;
            __syncthreads();  // previous compute done before LDS overwrite
            #pragma unroll
            for (int h = 0; h < 4; ++h) {
                const int row  = h * 32 + srow;
                const int kseg = slot ^ (row & 7);   // pre-swizzled source
                const unsigned short* ga = Zn + (size_t)(rowBase + row) * D_DIM + kbase + kseg * 8;
                const unsigned short* gb = Zn + (size_t)(colBase + row) * D_DIM + kbase + kseg * 8;
                char* la = (char*)Als + h * 4096 + (t & 192) * 16;  // wave-uniform base
                char* lb = (char*)Bls + h * 4096 + (t & 192) * 16;
                GLOAD16(ga, la);
                GLOAD16(gb, lb);
            }
            __syncthreads();  // compiler drains vmcnt before barrier

            #pragma unroll
            for (int ks = 0; ks < 2; ++ks) {
                bf16x8 af[4], bg[4];
                #pragma unroll
                for (int mi = 0; mi < 4; ++mi) {
                    const int row   = wm * 64 + mi * 16 + l15;
                    const int slotr = (ks * 4 + lhi) ^ (row & 7);  // swizzled read
                    af[mi] = *(const bf16x8*)((const char*)Als + row * 128 + slotr * 16);
                }
                #pragma unroll
                for (int ni = 0; ni < 4; ++ni) {
                    const int row   = wn * 64 + ni * 16 + l15;
                    const int slotr = (ks * 4 + lhi) ^ (row & 7);
                    bg[ni] = *(const bf16x8*)((const char*)Bls + row * 128 + slotr * 16);
                }
                #pragma unroll
                for (int mi = 0; mi < 4; ++mi)
                    #pragma unroll
                    for (int ni = 0; ni < 4; ++ni)
                        acc[mi][ni] = __builtin_amdgcn_mfma_f32_16x16x32_bf16(af[mi], bg[ni], acc[mi][ni], 0, 0, 0);
            }
        }

        // fused epilogue: rowsum += exp2(S * 10*log2e), diagonal masked exactly
        #pragma unroll
        for (int mi = 0; mi < 4; ++mi) {
            const int grow_base = rowBase + wm * 64 + mi * 16 + lhi * 4;  // C/D: row=(lane>>4)*4+reg
            #pragma unroll
            for (int ni = 0; ni < 4; ++ni) {
                const int gcol = colBase + wn * 64 + ni * 16 + l15;       // C/D: col=lane&15
                #pragma unroll
                for (int r = 0; r < 4; ++r) {
                    float arg = acc[mi][ni][r] * SCALE_L2E;
                    if (grow_base + r == gcol) arg = -1e30f;  // exp2 -> 0
                    rowsum[mi][r] += exp2f(arg);
                }
            }
        }
    }

    // reduce across the 16 lanes sharing (lane>>4); then one atomic per row-partial
    #pragma unroll
    for (int mi = 0; mi < 4; ++mi)
        #pragma unroll
        for (int r = 0; r < 4; ++r) {
            float s = rowsum[mi][r];
            s += __shfl_xor(s, 1);
            s += __shfl_xor(s, 2);
            s += __shfl_xor(s, 4);
            s += __shfl_xor(s, 8);
            if (l15 == 0)
                atomicAdd(&rowsum_g[rowBase + wm * 64 + mi * 16 + lhi * 4 + r], s);
        }
}

// ---------------- K3: lse_i = ln(rowsum_i), reduce sum ----------------
__global__ __launch_bounds__(256) void k_lse(const float* __restrict__ rowsum_g,
                                             float* __restrict__ sums) {
    const int i = blockIdx.x * 256 + threadIdx.x;
    float l = logf(rowsum_g[i]);
    #pragma unroll
    for (int off = 1; off < 64; off <<= 1) l += __shfl_xor(l, off);
    __shared__ float red[4];
    if ((threadIdx.x & 63) == 0) red[threadIdx.x >> 6] = l;
    __syncthreads();
    if (threadIdx.x == 0) atomicAdd(&sums[1], red[0] + red[1] + red[2] + red[3]);
}

// ---------------- K4: loss = mean(lse) - mean(pos) ----------------
__global__ void k_final(const float* __restrict__ sums, float* __restrict__ out) {
    out[0] = (sums[1] - sums[0]) * (1.0f / (float)N_ROWS);
}

extern "C" void kernel_launch(void* const* d_in, const int* in_sizes, int n_in,
                              void* d_out, int out_size, void* d_ws, size_t ws_size,
                              hipStream_t stream) {
    (void)in_sizes; (void)n_in; (void)out_size; (void)ws_size;
    const float* zi = (const float*)d_in[0];
    const float* zj = (const float*)d_in[1];

    // workspace layout
    const size_t ZN_BYTES  = (size_t)N_ROWS * D_DIM * 2;       // 8 MiB bf16
    unsigned short* Zn     = (unsigned short*)d_ws;
    float* rowsum_g        = (float*)((char*)d_ws + ZN_BYTES); // 8192 floats
    float* sums            = (float*)((char*)d_ws + ZN_BYTES + N_ROWS * 4); // [pos, lse]

    // zero accumulators every call (atomically accumulated)
    hipMemsetAsync((char*)d_ws + ZN_BYTES, 0, N_ROWS * 4 + 16, stream);

    k_normalize<<<B_ROWS, 256, 0, stream>>>(zi, zj, Zn, sums);
    k_gemm_lse<<<dim3(N_ROWS / COLS_PER_BLK, N_ROWS / BM), 256, 0, stream>>>(Zn, rowsum_g);
    k_lse<<<N_ROWS / 256, 256, 0, stream>>>(rowsum_g, sums);
    k_final<<<1, 1, 0, stream>>>(sums, (float*)d_out);
}

// Round 2
// 117.477 us; speedup vs baseline: 1.4245x; 1.4245x over previous
//
#include <hip/hip_runtime.h>
#include <stdint.h>

// Problem constants
#define D_DIM 512
#define B_ROWS 4096
#define N_ROWS 8192
// (1/TEMPERATURE) * log2(e) : exp(x/T) == exp2(x * SCALE_L2E)
#define SCALE_L2E 14.426950408889634f

#define BM 128
#define BK 64
#define NT (N_ROWS / BM)          // 64 tile rows/cols
#define NPAIRS (NT * (NT + 1) / 2)  // 2080, divisible by 8

typedef __attribute__((ext_vector_type(8))) __bf16 bf16x8;
typedef __attribute__((ext_vector_type(4))) float f32x4;

using gas1_t = const __attribute__((address_space(1))) void;
using las3_t = __attribute__((address_space(3))) void;
#define GLOAD16(g, l) __builtin_amdgcn_global_load_lds((gas1_t*)(g), (las3_t*)(l), 16, 0, 0)

// round-to-nearest-even float -> bf16 bits
__device__ __forceinline__ unsigned int f2bf(float f) {
    union { float f; unsigned int u; } v; v.f = f;
    unsigned int u = v.u;
    return (u + 0x7FFFu + ((u >> 16) & 1u)) >> 16;
}

// ---------------- K1: normalize rows -> bf16 Zn, write positive-pair logit contribution ----
// one wave per index i (handles zi[i] -> Zn[i] and zj[i] -> Zn[B+i]); 4 waves/block, no barrier
__global__ __launch_bounds__(256) void k_normalize(const float* __restrict__ zi,
                                                   const float* __restrict__ zj,
                                                   unsigned short* __restrict__ Zn,
                                                   float* __restrict__ pos) {
    const int t = threadIdx.x;
    const int lane = t & 63;
    const int i = blockIdx.x * 4 + (t >> 6);
    const float* pa = zi + (size_t)i * D_DIM + lane * 8;
    const float* pb = zj + (size_t)i * D_DIM + lane * 8;
    const float4 a0 = *(const float4*)pa;
    const float4 a1 = *(const float4*)(pa + 4);
    const float4 b0 = *(const float4*)pb;
    const float4 b1 = *(const float4*)(pb + 4);
    float ssi = a0.x*a0.x + a0.y*a0.y + a0.z*a0.z + a0.w*a0.w
              + a1.x*a1.x + a1.y*a1.y + a1.z*a1.z + a1.w*a1.w;
    float ssj = b0.x*b0.x + b0.y*b0.y + b0.z*b0.z + b0.w*b0.w
              + b1.x*b1.x + b1.y*b1.y + b1.z*b1.z + b1.w*b1.w;
    float dt  = a0.x*b0.x + a0.y*b0.y + a0.z*b0.z + a0.w*b0.w
              + a1.x*b1.x + a1.y*b1.y + a1.z*b1.z + a1.w*b1.w;
    #pragma unroll
    for (int off = 1; off < 64; off <<= 1) {
        ssi += __shfl_xor(ssi, off);
        ssj += __shfl_xor(ssj, off);
        dt  += __shfl_xor(dt,  off);
    }
    const float si = 1.0f / fmaxf(sqrtf(ssi), 1e-12f);
    const float sj = 1.0f / fmaxf(sqrtf(ssj), 1e-12f);
    uint4 pi, pj;
    pi.x = f2bf(a0.x * si) | (f2bf(a0.y * si) << 16);
    pi.y = f2bf(a0.z * si) | (f2bf(a0.w * si) << 16);
    pi.z = f2bf(a1.x * si) | (f2bf(a1.y * si) << 16);
    pi.w = f2bf(a1.z * si) | (f2bf(a1.w * si) << 16);
    pj.x = f2bf(b0.x * sj) | (f2bf(b0.y * sj) << 16);
    pj.y = f2bf(b0.z * sj) | (f2bf(b0.w * sj) << 16);
    pj.z = f2bf(b1.x * sj) | (f2bf(b1.y * sj) << 16);
    pj.w = f2bf(b1.z * sj) | (f2bf(b1.w * sj) << 16);
    *(uint4*)(Zn + (size_t)i * D_DIM + lane * 8) = pi;
    *(uint4*)(Zn + (size_t)(B_ROWS + i) * D_DIM + lane * 8) = pj;
    // positive logit appears twice in the loss (row i and row i+B): 2 * dot / T
    if (lane == 0) pos[i] = 20.0f * dt * si * sj;
}

// ---------------- K2: symmetric fused S = Zn·Zn^T + per-row sum(exp(S/T)) -----------------
// One 128x128 tile per block, only tile pairs (I <= J). Off-diagonal tiles scatter exp
// values into rowsum[row] AND rowsum[col] (symmetry). Diagonal tiles: masked, rows only.
// block = 256 threads = 4 waves (2x2), wave tile 64x64. XOR-swizzled LDS.
__global__ __launch_bounds__(256) void k_gemm_lse(const unsigned short* __restrict__ Zn,
                                                  float* __restrict__ rowsum_g) {
    __shared__ __align__(16) unsigned short Als[BM * BK];  // 16 KiB
    __shared__ __align__(16) unsigned short Bls[BM * BK];  // 16 KiB
    const int t    = threadIdx.x;
    const int lane = t & 63;
    const int w    = t >> 6;
    const int wm   = w >> 1, wn = w & 1;
    const int l15  = lane & 15, lhi = lane >> 4;

    // XCD-aware swizzle (bijective: NPAIRS % 8 == 0), then triangular decode
    int bid = (blockIdx.x & 7) * (NPAIRS / 8) + (blockIdx.x >> 3);
    int I = 0;
    while (bid >= NT - I) { bid -= NT - I; ++I; }
    const int J = I + bid;
    const int rowBase = I * BM, colBase = J * BM;
    const bool diag = (I == J);

    // staging geometry: thread t owns 16B at row=h*32+(t>>3), slot=(t&7) in a 128B row
    const int srow = t >> 3;
    const int slot = t & 7;

    f32x4 acc[4][4];
    float rowsum[4][4];
    #pragma unroll
    for (int a = 0; a < 4; ++a)
        #pragma unroll
        for (int b = 0; b < 4; ++b) {
            rowsum[a][b] = 0.0f;
            #pragma unroll
            for (int q = 0; q < 4; ++q) acc[a][b][q] = 0.0f;
        }

    for (int kc = 0; kc < D_DIM / BK; ++kc) {
        const int kbase = kc * BK;
        __syncthreads();  // previous compute done before LDS overwrite
        #pragma unroll
        for (int h = 0; h < 4; ++h) {
            const int row  = h * 32 + srow;
            const int kseg = slot ^ (row & 7);   // pre-swizzled source
            const unsigned short* ga = Zn + (size_t)(rowBase + row) * D_DIM + kbase + kseg * 8;
            char* la = (char*)Als + h * 4096 + (t & 192) * 16;  // wave-uniform base
            GLOAD16(ga, la);
            if (!diag) {
                const unsigned short* gb = Zn + (size_t)(colBase + row) * D_DIM + kbase + kseg * 8;
                char* lb = (char*)Bls + h * 4096 + (t & 192) * 16;
                GLOAD16(gb, lb);
            }
        }
        __syncthreads();  // compiler drains vmcnt before barrier

        const char* Bbase = diag ? (const char*)Als : (const char*)Bls;
        #pragma unroll
        for (int ks = 0; ks < 2; ++ks) {
            bf16x8 af[4], bg[4];
            #pragma unroll
            for (int mi = 0; mi < 4; ++mi) {
                const int row   = wm * 64 + mi * 16 + l15;
                const int slotr = (ks * 4 + lhi) ^ (row & 7);  // swizzled read
                af[mi] = *(const bf16x8*)((const char*)Als + row * 128 + slotr * 16);
            }
            #pragma unroll
            for (int ni = 0; ni < 4; ++ni) {
                const int row   = wn * 64 + ni * 16 + l15;
                const int slotr = (ks * 4 + lhi) ^ (row & 7);
                bg[ni] = *(const bf16x8*)(Bbase + row * 128 + slotr * 16);
            }
            #pragma unroll
            for (int mi = 0; mi < 4; ++mi)
                #pragma unroll
                for (int ni = 0; ni < 4; ++ni)
                    acc[mi][ni] = __builtin_amdgcn_mfma_f32_16x16x32_bf16(af[mi], bg[ni], acc[mi][ni], 0, 0, 0);
        }
    }

    // epilogue: e = exp2(S * 10*log2e); C/D layout: col=lane&15, row=(lane>>4)*4+reg
    if (diag) {
        #pragma unroll
        for (int mi = 0; mi < 4; ++mi) {
            const int grow_base = rowBase + wm * 64 + mi * 16 + lhi * 4;
            #pragma unroll
            for (int ni = 0; ni < 4; ++ni) {
                const int gcol = colBase + wn * 64 + ni * 16 + l15;
                #pragma unroll
                for (int r = 0; r < 4; ++r) {
                    float arg = acc[mi][ni][r] * SCALE_L2E;
                    if (grow_base + r == gcol) arg = -1e30f;  // exp2 -> 0
                    rowsum[mi][r] += exp2f(arg);
                }
            }
        }
    } else {
        float colsum[4] = {0.0f, 0.0f, 0.0f, 0.0f};
        #pragma unroll
        for (int mi = 0; mi < 4; ++mi)
            #pragma unroll
            for (int ni = 0; ni < 4; ++ni)
                #pragma unroll
                for (int r = 0; r < 4; ++r) {
                    const float e = exp2f(acc[mi][ni][r] * SCALE_L2E);
                    rowsum[mi][r] += e;
                    colsum[ni] += e;
                }
        // column sums: reduce across lhi groups (rows), lanes with lhi==0 hold col l15
        #pragma unroll
        for (int ni = 0; ni < 4; ++ni) {
            float c = colsum[ni];
            c += __shfl_xor(c, 16);
            c += __shfl_xor(c, 32);
            if (lhi == 0)
                atomicAdd(&rowsum_g[colBase + wn * 64 + ni * 16 + l15], c);
        }
    }

    // row sums: reduce across the 16 lanes sharing lhi, one atomic per row-partial
    #pragma unroll
    for (int mi = 0; mi < 4; ++mi)
        #pragma unroll
        for (int r = 0; r < 4; ++r) {
            float s = rowsum[mi][r];
            s += __shfl_xor(s, 1);
            s += __shfl_xor(s, 2);
            s += __shfl_xor(s, 4);
            s += __shfl_xor(s, 8);
            if (l15 == 0)
                atomicAdd(&rowsum_g[rowBase + wm * 64 + mi * 16 + lhi * 4 + r], s);
        }
}

// ---------------- K3: sums[1] += sum(ln(rowsum_i)); sums[0] += sum(pos) ----------------
__global__ __launch_bounds__(256) void k_lse(const float* __restrict__ rowsum_g,
                                             const float* __restrict__ pos,
                                             float* __restrict__ sums) {
    const int i = blockIdx.x * 256 + threadIdx.x;
    float l = logf(rowsum_g[i]);
    float p = (i < B_ROWS) ? pos[i] : 0.0f;
    #pragma unroll
    for (int off = 1; off < 64; off <<= 1) {
        l += __shfl_xor(l, off);
        p += __shfl_xor(p, off);
    }
    __shared__ float red[2][4];
    if ((threadIdx.x & 63) == 0) {
        red[0][threadIdx.x >> 6] = l;
        red[1][threadIdx.x >> 6] = p;
    }
    __syncthreads();
    if (threadIdx.x == 0) {
        atomicAdd(&sums[1], red[0][0] + red[0][1] + red[0][2] + red[0][3]);
        atomicAdd(&sums[0], red[1][0] + red[1][1] + red[1][2] + red[1][3]);
    }
}

// ---------------- K4: loss = mean(lse) - mean(pos) ----------------
__global__ void k_final(const float* __restrict__ sums, float* __restrict__ out) {
    out[0] = (sums[1] - sums[0]) * (1.0f / (float)N_ROWS);
}

extern "C" void kernel_launch(void* const* d_in, const int* in_sizes, int n_in,
                              void* d_out, int out_size, void* d_ws, size_t ws_size,
                              hipStream_t stream) {
    (void)in_sizes; (void)n_in; (void)out_size; (void)ws_size;
    const float* zi = (const float*)d_in[0];
    const float* zj = (const float*)d_in[1];

    // workspace layout
    const size_t ZN_BYTES = (size_t)N_ROWS * D_DIM * 2;            // 8 MiB bf16
    unsigned short* Zn    = (unsigned short*)d_ws;
    float* rowsum_g       = (float*)((char*)d_ws + ZN_BYTES);                       // 8192 f32
    float* pos            = (float*)((char*)d_ws + ZN_BYTES + N_ROWS * 4);          // 4096 f32
    float* sums           = (float*)((char*)d_ws + ZN_BYTES + N_ROWS * 4 + B_ROWS * 4); // [pos, lse]

    // zero the atomically-accumulated region (rowsum + pos + sums)
    hipMemsetAsync((char*)d_ws + ZN_BYTES, 0, N_ROWS * 4 + B_ROWS * 4 + 16, stream);

    k_normalize<<<B_ROWS / 4, 256, 0, stream>>>(zi, zj, Zn, pos);
    k_gemm_lse<<<NPAIRS, 256, 0, stream>>>(Zn, rowsum_g);
    k_lse<<<N_ROWS / 256, 256, 0, stream>>>(rowsum_g, pos, sums);
    k_final<<<1, 1, 0, stream>>>(sums, (float*)d_out);
}